// Round 1
// baseline (3040.889 us; speedup 1.0000x reference)
//
#include <hip/hip_runtime.h>
#include <hip/hip_bf16.h>

#define NN 50000
#define EE 800000
#define ET 16   // edges per block in edge kernel

typedef unsigned int u32;

// ---- ordered-uint mapping for float atomicMax ----
__device__ __forceinline__ u32 fmap(float x){
  u32 b = __float_as_uint(x);
  return (b & 0x80000000u) ? ~b : (b | 0x80000000u);
}
__device__ __forceinline__ float funmap(u32 u){
  u32 b = (u & 0x80000000u) ? (u ^ 0x80000000u) : ~u;
  return __uint_as_float(b);
}

// ---- dtype-hedged loads ----
template<bool BF>
__device__ __forceinline__ float ldf(const void* p, int i){
  if constexpr (BF) return __bfloat162float(((const __hip_bfloat16*)p)[i]);
  else              return ((const float*)p)[i];
}
__device__ __forceinline__ int gidx(const int* ei, int pos, bool i64){
  return i64 ? ei[2*pos] : ei[pos];   // low word (values < 2^31)
}

// ---- dtype / index-width detection ----
__global__ void k_detect(const u32* lnw, const u32* ei, int* flags){
  if (threadIdx.x == 0){
    flags[0] = (lnw[0] == 0x3F803F80u) ? 1 : 0;                 // bf16 floats?
    flags[1] = ((ei[1] | ei[3] | ei[5] | ei[7]) == 0u) ? 1 : 0; // int64 indices?
  }
}

// ================= Q MLP: one row per 128-thread block =================
template<bool BF>
__device__ void q_body(const void* h, const void* W1, const void* b1,
                       const void* lnw, const void* lnb,
                       const void* W2, const void* b2, float* qout){
  __shared__ float x[128];
  __shared__ float hd[128];
  __shared__ float2 red[128];
  const int c = threadIdx.x;
  const int row = blockIdx.x;
  x[c] = ldf<BF>(h, row*128 + c);
  __syncthreads();
  float a = 0.f;
  #pragma unroll 4
  for (int j=0;j<128;j++) a = fmaf(x[j], ldf<BF>(W1, j*128+c), a);
  a += ldf<BF>(b1, c);
  red[c] = make_float2(a, a*a);
  __syncthreads();
  for (int s=64; s>0; s>>=1){
    if (c < s){ red[c].x += red[c+s].x; red[c].y += red[c+s].y; }
    __syncthreads();
  }
  float mu  = red[0].x * (1.f/128.f);
  float var = red[0].y * (1.f/128.f) - mu*mu;
  float sc  = rsqrtf(var + 1e-5f);
  a = (a - mu)*sc*ldf<BF>(lnw,c) + ldf<BF>(lnb,c);
  a = fmaxf(a, 0.f);
  hd[c] = a;
  __syncthreads();
  float o = ldf<BF>(b2, c);
  #pragma unroll 4
  for (int j=0;j<128;j++) o = fmaf(hd[j], ldf<BF>(W2, j*128+c), o);
  qout[row*128 + c] = o;
}
__global__ void __launch_bounds__(128)
k_q(const void* h, const void* W1, const void* b1, const void* lnw, const void* lnb,
    const void* W2, const void* b2, float* qout, const int* flags){
  if (flags[0]) q_body<true >(h,W1,b1,lnw,lnb,W2,b2,qout);
  else          q_body<false>(h,W1,b1,lnw,lnb,W2,b2,qout);
}

// ================= Edge kernel: K/V MLPs + scores + segmax =================
template<bool BF>
__device__ void edge_body(const void* h, const void* rfeat, const void* efeat,
                          const int* ei, bool i64,
                          const void* ewW, const void* ewb,
                          const void* kW1, const void* kb1, const void* klnw, const void* klnb,
                          const void* kW2, const void* kb2,
                          const void* vW1, const void* vb1, const void* vlnw, const void* vlnb,
                          const void* vW2, const void* vb2,
                          const float* qws, float* scw, float* vsw, u32* smx){
  __shared__ float buf[280*ET];          // phase A: kv_input [j][e]; later hdn [c][e]; later k/v [c][e]
  __shared__ int   dste[ET], srce[ET];
  __shared__ float ewv[ET];
  __shared__ float mus[32], scs[32];
  __shared__ float2 redp[256];
  const int t  = threadIdx.x;
  const int e0 = blockIdx.x*ET;

  if (t < ET)          dste[t]    = gidx(ei, EE + e0 + t, i64);
  else if (t < 2*ET)   srce[t-ET] = gidx(ei, e0 + (t-ET), i64);
  __syncthreads();

  // ---- stage kv_input = [edge_feat(4) | r_feat(20) | h[dst](128) | h[src](128)] as buf[j*ET+e]
  if (t < 64){ int e = t>>2, j = t&3; buf[j*ET+e] = ldf<BF>(efeat, (e0+e)*4 + j); }
  for (int idx=t; idx<20*ET; idx+=256){
    int e = idx/20, j = idx - 20*e;
    buf[(4+j)*ET+e] = ldf<BF>(rfeat, (e0+e)*20 + j);
  }
  #pragma unroll
  for (int r=0;r<8;r++){ int idx = r*256+t; int e = idx>>7, j = idx&127;
    buf[(24+j)*ET+e]  = ldf<BF>(h, dste[e]*128 + j); }
  #pragma unroll
  for (int r=0;r<8;r++){ int idx = r*256+t; int e = idx>>7, j = idx&127;
    buf[(152+j)*ET+e] = ldf<BF>(h, srce[e]*128 + j); }
  __syncthreads();

  // ---- edge scalar weight: sigmoid(r_feat @ ew_W + ew_b) / H
  if (t < ET){
    float a = ldf<BF>(ewb, 0);
    #pragma unroll
    for (int j=0;j<20;j++) a = fmaf(buf[(4+j)*ET + t], ldf<BF>(ewW, j), a);
    ewv[t] = (1.f/(1.f + expf(-a))) * (1.f/16.f);
  }

  // ---- layer 1: col c (0..127 -> xk, 128..255 -> xv), 16 edges per thread
  const int c = t;
  float acc[ET];
  #pragma unroll
  for (int e=0;e<ET;e++) acc[e] = 0.f;
  for (int j=0;j<280;j++){
    float w = (c<128) ? ldf<BF>(kW1, j*128+c) : ldf<BF>(vW1, j*128 + (c-128));
    const float4* xr = (const float4*)&buf[j*ET];
    #pragma unroll
    for (int e4=0;e4<4;e4++){
      float4 xv = xr[e4];
      acc[e4*4+0] = fmaf(w, xv.x, acc[e4*4+0]);
      acc[e4*4+1] = fmaf(w, xv.y, acc[e4*4+1]);
      acc[e4*4+2] = fmaf(w, xv.z, acc[e4*4+2]);
      acc[e4*4+3] = fmaf(w, xv.w, acc[e4*4+3]);
    }
  }
  { float bb = (c<128) ? ldf<BF>(kb1,c) : ldf<BF>(vb1,c-128);
    #pragma unroll
    for (int e=0;e<ET;e++) acc[e] += bb; }
  __syncthreads();          // kv_input reads (incl. ew) done -> reuse buf
  #pragma unroll
  for (int e=0;e<ET;e++) buf[c*ET+e] = acc[e];
  __syncthreads();

  // ---- LayerNorm stats per (branch, edge): 32 groups, 8 partial-threads each
  { int p = t>>3, l8 = t&7; int b = p>>4, eidx = p&15;
    float s=0.f, s2=0.f;
    for (int cc=l8; cc<128; cc+=8){
      float v = buf[(b*128+cc)*ET + eidx];
      s += v; s2 = fmaf(v, v, s2);
    }
    redp[t] = make_float2(s, s2);
  }
  __syncthreads();
  if (t < 32){
    float s=0.f, s2=0.f;
    #pragma unroll
    for (int k=0;k<8;k++){ float2 f = redp[t*8+k]; s += f.x; s2 += f.y; }
    float mu  = s  * (1.f/128.f);
    float var = s2 * (1.f/128.f) - mu*mu;
    mus[t] = mu; scs[t] = rsqrtf(var + 1e-5f);
  }
  __syncthreads();
  { int b = c>>7;
    float lw = (c<128) ? ldf<BF>(klnw,c) : ldf<BF>(vlnw,c-128);
    float lb = (c<128) ? ldf<BF>(klnb,c) : ldf<BF>(vlnb,c-128);
    #pragma unroll
    for (int e=0;e<ET;e++){
      int p = b*16 + e;
      float v = (acc[e] - mus[p])*scs[p]*lw + lb;
      buf[c*ET+e] = fmaxf(v, 0.f);
    }
  }
  __syncthreads();

  // ---- layer 2: k cols (c<128), v cols (128<=c<144)
  float o[ET];
  if (c < 128){
    float bb = ldf<BF>(kb2, c);
    #pragma unroll
    for (int e=0;e<ET;e++) o[e] = bb;
    for (int j=0;j<128;j++){
      float w = ldf<BF>(kW2, j*128+c);
      const float4* xr = (const float4*)&buf[j*ET];
      #pragma unroll
      for (int e4=0;e4<4;e4++){
        float4 xv = xr[e4];
        o[e4*4+0] = fmaf(w, xv.x, o[e4*4+0]);
        o[e4*4+1] = fmaf(w, xv.y, o[e4*4+1]);
        o[e4*4+2] = fmaf(w, xv.z, o[e4*4+2]);
        o[e4*4+3] = fmaf(w, xv.w, o[e4*4+3]);
      }
    }
  } else if (c < 144){
    int cv = c - 128;
    float bb = ldf<BF>(vb2, cv);
    #pragma unroll
    for (int e=0;e<ET;e++) o[e] = bb;
    for (int j=0;j<128;j++){
      float w = ldf<BF>(vW2, j*16+cv);
      const float4* xr = (const float4*)&buf[(128+j)*ET];
      #pragma unroll
      for (int e4=0;e4<4;e4++){
        float4 xv = xr[e4];
        o[e4*4+0] = fmaf(w, xv.x, o[e4*4+0]);
        o[e4*4+1] = fmaf(w, xv.y, o[e4*4+1]);
        o[e4*4+2] = fmaf(w, xv.z, o[e4*4+2]);
        o[e4*4+3] = fmaf(w, xv.w, o[e4*4+3]);
      }
    }
  }
  __syncthreads();
  if (c < 144){
    #pragma unroll
    for (int e=0;e<ET;e++) buf[c*ET+e] = o[e];   // k rows 0..127, vraw rows 128..143
  }
  __syncthreads();

  // ---- scores + segment max + vs
  { int e = t>>4, hh = t&15;
    int ge = e0 + e;
    int d  = dste[e];
    const float* qr = qws + (size_t)d*128 + hh*8;
    float4 q0 = *(const float4*)qr;
    float4 q1 = *(const float4*)(qr+4);
    float s = q0.x*buf[(hh*8+0)*ET+e] + q0.y*buf[(hh*8+1)*ET+e]
            + q0.z*buf[(hh*8+2)*ET+e] + q0.w*buf[(hh*8+3)*ET+e]
            + q1.x*buf[(hh*8+4)*ET+e] + q1.y*buf[(hh*8+5)*ET+e]
            + q1.z*buf[(hh*8+6)*ET+e] + q1.w*buf[(hh*8+7)*ET+e];
    s *= 0.35355339059327373f;                 // 1/sqrt(8)
    scw[ge*16 + hh] = s;
    atomicMax(&smx[d*16 + hh], fmap(s));
    vsw[ge*16 + hh] = buf[(128+hh)*ET + e] * ewv[e];
  }
}
__global__ void __launch_bounds__(256)
k_edge(const void* h, const void* rfeat, const void* efeat, const int* ei,
       const void* ewW, const void* ewb,
       const void* kW1, const void* kb1, const void* klnw, const void* klnb,
       const void* kW2, const void* kb2,
       const void* vW1, const void* vb1, const void* vlnw, const void* vlnb,
       const void* vW2, const void* vb2,
       const float* qws, float* scw, float* vsw, u32* smx, const int* flags){
  bool i64 = flags[1] != 0;
  if (flags[0]) edge_body<true >(h,rfeat,efeat,ei,i64,ewW,ewb,kW1,kb1,klnw,klnb,kW2,kb2,vW1,vb1,vlnw,vlnb,vW2,vb2,qws,scw,vsw,smx);
  else          edge_body<false>(h,rfeat,efeat,ei,i64,ewW,ewb,kW1,kb1,klnw,klnb,kW2,kb2,vW1,vb1,vlnw,vlnb,vW2,vb2,qws,scw,vsw,smx);
}

// ================= exp + denom =================
__global__ void __launch_bounds__(256)
k_expden(const int* ei, const u32* smx, float* scw, float* den, const int* flags){
  int t = blockIdx.x*256 + threadIdx.x;
  if (t >= EE*16) return;
  bool i64 = flags[1] != 0;
  int e = t>>4, hh = t&15;
  int d = gidx(ei, EE + e, i64);
  float m  = funmap(smx[d*16 + hh]);
  float ex = expf(scw[t] - m);
  scw[t] = ex;
  atomicAdd(&den[d*16 + hh], ex);
}

// ================= alpha*vs reduce over heads + scatter into out =================
__global__ void __launch_bounds__(256)
k_out(const int* ei, const void* relx, const float* scw, const float* vsw,
      const float* den, float* oac, const int* flags){
  int t = blockIdx.x*256 + threadIdx.x;
  if (t >= EE*16) return;
  bool bf  = flags[0] != 0;
  bool i64 = flags[1] != 0;
  int e = t>>4, hh = t&15;
  int d = gidx(ei, EE + e, i64);
  float a = (scw[t] / den[d*16 + hh]) * vsw[t];
  a += __shfl_xor(a, 8, 16);
  a += __shfl_xor(a, 4, 16);
  a += __shfl_xor(a, 2, 16);
  a += __shfl_xor(a, 1, 16);
  if (hh < 3){
    float r = bf ? __bfloat162float(((const __hip_bfloat16*)relx)[e*3+hh])
                 : ((const float*)relx)[e*3+hh];
    atomicAdd(&oac[d*3 + hh], a * r);
  }
}

// ================= finalize =================
__global__ void __launch_bounds__(256)
k_fin(const float* oac, void* dout, const int* flags){
  int t = blockIdx.x*256 + threadIdx.x;
  if (t >= NN*3) return;
  if (flags[0]) ((__hip_bfloat16*)dout)[t] = __float2bfloat16(oac[t]);
  else          ((float*)dout)[t] = oac[t];
}

extern "C" void kernel_launch(void* const* d_in, const int* in_sizes, int n_in,
                              void* d_out, int out_size, void* d_ws, size_t ws_size,
                              hipStream_t stream){
  const void* h     = d_in[0];
  const void* relx  = d_in[1];
  const void* rfeat = d_in[2];
  const void* efeat = d_in[3];
  const int*  ei    = (const int*)d_in[4];
  const void* ewW   = d_in[5];
  const void* ewb   = d_in[6];
  const void* kW1 = d_in[7],  *kb1 = d_in[8],  *klnw = d_in[9],  *klnb = d_in[10], *kW2 = d_in[11], *kb2 = d_in[12];
  const void* vW1 = d_in[13], *vb1 = d_in[14], *vlnw = d_in[15], *vlnb = d_in[16], *vW2 = d_in[17], *vb2 = d_in[18];
  const void* qW1 = d_in[19], *qb1 = d_in[20], *qlnw = d_in[21], *qlnb = d_in[22], *qW2 = d_in[23], *qb2 = d_in[24];

  float* qws = (float*)d_ws;                         // N*128 f32
  float* scw = qws + (size_t)NN*128;                 // E*16  f32 (scores -> exp in place)
  float* vsw = scw + (size_t)EE*16;                  // E*16  f32 (vraw*sigmoid(ew)/H)
  u32*   smx = (u32*)(vsw + (size_t)EE*16);          // N*16  ordered-uint max
  float* den = (float*)(smx + (size_t)NN*16);        // N*16  f32
  float* oac = den + (size_t)NN*16;                  // N*3   f32
  int* flags = (int*)(oac + (size_t)NN*3);           // 2 ints

  hipMemsetAsync(smx, 0, ((size_t)NN*16*2 + (size_t)NN*3)*sizeof(float), stream);
  k_detect<<<1, 64, 0, stream>>>((const u32*)klnw, (const u32*)ei, flags);
  k_q<<<NN, 128, 0, stream>>>(h, qW1, qb1, qlnw, qlnb, qW2, qb2, qws, flags);
  k_edge<<<EE/ET, 256, 0, stream>>>(h, rfeat, efeat, ei, ewW, ewb,
                                    kW1,kb1,klnw,klnb,kW2,kb2,
                                    vW1,vb1,vlnw,vlnb,vW2,vb2,
                                    qws, scw, vsw, smx, flags);
  k_expden<<<(EE*16)/256, 256, 0, stream>>>(ei, smx, scw, den, flags);
  k_out   <<<(EE*16)/256, 256, 0, stream>>>(ei, relx, scw, vsw, den, oac, flags);
  k_fin<<<(NN*3 + 255)/256, 256, 0, stream>>>(oac, d_out, flags);
}

// Round 2
// 1897.562 us; speedup vs baseline: 1.6025x; 1.6025x over previous
//
#include <hip/hip_runtime.h>
#include <hip/hip_bf16.h>

#define NN 50000
#define EE 800000
#define ET 16   // edges per block in edge kernel
#define NT 16   // nodes per block in k_node
#define QT 8    // rows per block in k_q

typedef unsigned int u32;

// ---- ordered-uint mapping for float atomicMax ----
__device__ __forceinline__ u32 fmap(float x){
  u32 b = __float_as_uint(x);
  return (b & 0x80000000u) ? ~b : (b | 0x80000000u);
}
__device__ __forceinline__ float funmap(u32 u){
  u32 b = (u & 0x80000000u) ? (u ^ 0x80000000u) : ~u;
  return __uint_as_float(b);
}

// ---- dtype-hedged loads ----
template<bool BF>
__device__ __forceinline__ float ldf(const void* p, int i){
  if constexpr (BF) return __bfloat162float(((const __hip_bfloat16*)p)[i]);
  else              return ((const float*)p)[i];
}
__device__ __forceinline__ int gidx(const int* ei, int pos, bool i64){
  return i64 ? ei[2*pos] : ei[pos];
}

__global__ void k_detect(const u32* lnw, const u32* ei, int* flags){
  if (threadIdx.x == 0){
    flags[0] = (lnw[0] == 0x3F803F80u) ? 1 : 0;
    flags[1] = ((ei[1] | ei[3] | ei[5] | ei[7]) == 0u) ? 1 : 0;
  }
}

// ================= node precompute: hkd = h @ W1[24:152], hks = h @ W1[152:280]
// (k-branch cols 0..127, v-branch cols 128..255)
template<bool BF>
__device__ void node_body(const void* h, const void* kW1, const void* vW1,
                          float* hkd, float* hks){
  __shared__ float x[128*20];   // [j][n], stride 20 (float4-aligned, conflict-light)
  const int t  = threadIdx.x;
  const int n0 = blockIdx.x*NT;
  #pragma unroll
  for (int r=0;r<8;r++){ int idx=r*256+t; int n=idx>>7, j=idx&127;
    x[j*20+n] = ldf<BF>(h, (n0+n)*128 + j); }
  __syncthreads();
  const bool kb = (t < 128);
  const void* W = kb ? kW1 : vW1;
  const int  cc = kb ? t : t-128;
  float ad[NT], as[NT];
  #pragma unroll
  for (int e=0;e<NT;e++){ ad[e]=0.f; as[e]=0.f; }
  for (int j=0;j<128;j++){
    float wd = ldf<BF>(W, (24+j)*128 + cc);
    float ws = ldf<BF>(W, (152+j)*128 + cc);
    const float4* xr = (const float4*)&x[j*20];
    #pragma unroll
    for (int e4=0;e4<4;e4++){
      float4 xv = xr[e4];
      ad[e4*4+0]=fmaf(wd,xv.x,ad[e4*4+0]); as[e4*4+0]=fmaf(ws,xv.x,as[e4*4+0]);
      ad[e4*4+1]=fmaf(wd,xv.y,ad[e4*4+1]); as[e4*4+1]=fmaf(ws,xv.y,as[e4*4+1]);
      ad[e4*4+2]=fmaf(wd,xv.z,ad[e4*4+2]); as[e4*4+2]=fmaf(ws,xv.z,as[e4*4+2]);
      ad[e4*4+3]=fmaf(wd,xv.w,ad[e4*4+3]); as[e4*4+3]=fmaf(ws,xv.w,as[e4*4+3]);
    }
  }
  #pragma unroll
  for (int e=0;e<NT;e++){
    hkd[(n0+e)*256 + t] = ad[e];
    hks[(n0+e)*256 + t] = as[e];
  }
}
__global__ void __launch_bounds__(256)
k_node(const void* h, const void* kW1, const void* vW1, float* hkd, float* hks, const int* flags){
  if (flags[0]) node_body<true >(h,kW1,vW1,hkd,hks);
  else          node_body<false>(h,kW1,vW1,hkd,hks);
}

// ================= Q MLP: 8 rows per 256-thread block =================
template<bool BF>
__device__ void q_body(const void* h, const void* W1, const void* b1,
                       const void* lnw, const void* lnb,
                       const void* W2, const void* b2, float* qws){
  __shared__ float x[128*12];   // [j][n]
  __shared__ float y[QT*128];   // [row][c]
  __shared__ float2 redp[256];
  __shared__ float mus[QT], scs[QT];
  const int t = threadIdx.x, c = t&127, half = t>>7;
  const int n0 = blockIdx.x*QT;
  #pragma unroll
  for (int r=0;r<4;r++){ int idx=r*256+t; int n=idx>>7, j=idx&127;
    x[j*12+n] = ldf<BF>(h, (n0+n)*128 + j); }
  __syncthreads();
  float a[4];
  { float bb = ldf<BF>(b1,c);
    #pragma unroll
    for (int r=0;r<4;r++) a[r]=bb; }
  for (int j=0;j<128;j++){
    float w = ldf<BF>(W1, j*128+c);
    float4 xv = *(const float4*)&x[j*12 + half*4];
    a[0]=fmaf(w,xv.x,a[0]); a[1]=fmaf(w,xv.y,a[1]);
    a[2]=fmaf(w,xv.z,a[2]); a[3]=fmaf(w,xv.w,a[3]);
  }
  #pragma unroll
  for (int r=0;r<4;r++) y[(half*4+r)*128 + c] = a[r];
  __syncthreads();
  { int p=t>>5, l32=t&31;
    float s=0.f,s2=0.f;
    #pragma unroll
    for (int k=0;k<4;k++){ float v=y[p*128 + l32 + 32*k]; s+=v; s2=fmaf(v,v,s2); }
    redp[t]=make_float2(s,s2); }
  __syncthreads();
  if (t<QT){
    float s=0.f,s2=0.f;
    for (int i=0;i<32;i++){ float2 f=redp[t*32+i]; s+=f.x; s2+=f.y; }
    float mu=s*(1.f/128.f), var=s2*(1.f/128.f)-mu*mu;
    mus[t]=mu; scs[t]=rsqrtf(var+1e-5f);
  }
  __syncthreads();
  { float lw=ldf<BF>(lnw,c), lb=ldf<BF>(lnb,c);
    #pragma unroll
    for (int r=0;r<4;r++){ int row=half*4+r;
      float v=(a[r]-mus[row])*scs[row]*lw+lb;
      y[row*128+c]=fmaxf(v,0.f); } }
  __syncthreads();
  float o[4];
  { float bb=ldf<BF>(b2,c);
    #pragma unroll
    for (int r=0;r<4;r++) o[r]=bb; }
  for (int j4=0;j4<32;j4++){
    float w0=ldf<BF>(W2,(j4*4+0)*128+c);
    float w1=ldf<BF>(W2,(j4*4+1)*128+c);
    float w2=ldf<BF>(W2,(j4*4+2)*128+c);
    float w3=ldf<BF>(W2,(j4*4+3)*128+c);
    #pragma unroll
    for (int r=0;r<4;r++){
      float4 xv=*(const float4*)&y[(half*4+r)*128 + j4*4];
      o[r]=fmaf(w0,xv.x,o[r]); o[r]=fmaf(w1,xv.y,o[r]);
      o[r]=fmaf(w2,xv.z,o[r]); o[r]=fmaf(w3,xv.w,o[r]);
    }
  }
  #pragma unroll
  for (int r=0;r<4;r++) qws[(n0+half*4+r)*128 + c] = o[r];
}
__global__ void __launch_bounds__(256)
k_q(const void* h, const void* W1, const void* b1, const void* lnw, const void* lnb,
    const void* W2, const void* b2, float* qws, const int* flags){
  if (flags[0]) q_body<true >(h,W1,b1,lnw,lnb,W2,b2,qws);
  else          q_body<false>(h,W1,b1,lnw,lnb,W2,b2,qws);
}

// ================= Edge kernel =================
template<bool BF>
__device__ void edge_body(const void* rfeat, const void* efeat, const int* ei, bool i64,
                          const void* ewW, const void* ewb,
                          const void* kW1, const void* kb1, const void* klnw, const void* klnb,
                          const void* kW2, const void* kb2,
                          const void* vW1, const void* vb1, const void* vlnw, const void* vlnb,
                          const void* vW2, const void* vb2,
                          const float* hkd, const float* hks, const float* qws,
                          float* scw, float* vsw, u32* smx){
  __shared__ float srf[24*ET];     // [j][e]  (edge_feat | r_feat)
  __shared__ float hdn[ET*256];    // [e][c]
  __shared__ float vpart[2*16*ET]; // [half][h][e]
  __shared__ int   dste[ET], srce[ET];
  __shared__ float ewv[ET];
  __shared__ float mus[2*ET], scs[2*ET];
  __shared__ float2 redp[256];
  const int t  = threadIdx.x;
  const int e0 = blockIdx.x*ET;

  if (t < ET)        dste[t]    = gidx(ei, EE + e0 + t, i64);
  else if (t < 2*ET) srce[t-ET] = gidx(ei, e0 + (t-ET), i64);
  if (t >= 64 && t < 128){ int q=t-64; int e=q>>2, j=q&3;
    srf[j*ET+e] = ldf<BF>(efeat, (e0+e)*4 + j); }
  for (int idx=t; idx<20*ET; idx+=256){
    int e=idx/20, j=idx-20*e;
    srf[(4+j)*ET+e] = ldf<BF>(rfeat, (e0+e)*20 + j);
  }
  __syncthreads();

  if (t < ET){
    float aw = ldf<BF>(ewb, 0);
    #pragma unroll
    for (int j=0;j<20;j++) aw = fmaf(srf[(4+j)*ET+t], ldf<BF>(ewW, j), aw);
    ewv[t] = (1.f/(1.f + expf(-aw))) * (1.f/16.f);
  }

  const int  c  = t;
  const bool kb = (c < 128);
  const int  cc = kb ? c : c-128;

  // ---- layer 1: gather-add + small 24-dim GEMM
  float acc[ET];
  { float bb = kb ? ldf<BF>(kb1,cc) : ldf<BF>(vb1,cc);
    #pragma unroll
    for (int e=0;e<ET;e++) acc[e]=bb; }
  #pragma unroll
  for (int e=0;e<ET;e++)
    acc[e] += hkd[dste[e]*256 + c] + hks[srce[e]*256 + c];
  { const void* W1 = kb ? kW1 : vW1;
    for (int j=0;j<24;j++){
      float w = ldf<BF>(W1, j*128+cc);
      const float4* xr = (const float4*)&srf[j*ET];
      #pragma unroll
      for (int e4=0;e4<4;e4++){
        float4 xv = xr[e4];
        acc[e4*4+0]=fmaf(w,xv.x,acc[e4*4+0]);
        acc[e4*4+1]=fmaf(w,xv.y,acc[e4*4+1]);
        acc[e4*4+2]=fmaf(w,xv.z,acc[e4*4+2]);
        acc[e4*4+3]=fmaf(w,xv.w,acc[e4*4+3]);
      }
    }
  }
  #pragma unroll
  for (int e=0;e<ET;e++) hdn[e*256+c] = acc[e];
  __syncthreads();

  // ---- LayerNorm stats (32 groups = 2 branch x 16 edges)
  { int p=t>>3, l8=t&7; int b=p>>4, eidx=p&15;
    float s=0.f,s2=0.f;
    #pragma unroll
    for (int k=0;k<16;k++){ float v=hdn[eidx*256 + b*128 + l8 + 8*k]; s+=v; s2=fmaf(v,v,s2); }
    redp[t]=make_float2(s,s2);
  }
  __syncthreads();
  if (t<32){
    float s=0.f,s2=0.f;
    #pragma unroll
    for (int kk=0;kk<8;kk++){ float2 f=redp[t*8+kk]; s+=f.x; s2+=f.y; }
    float mu=s*(1.f/128.f), var=s2*(1.f/128.f)-mu*mu;
    mus[t]=mu; scs[t]=rsqrtf(var+1e-5f);
  }
  __syncthreads();
  { float lw = kb ? ldf<BF>(klnw,cc) : ldf<BF>(vlnw,cc);
    float lb = kb ? ldf<BF>(klnb,cc) : ldf<BF>(vlnb,cc);
    int b = kb ? 0 : 16;
    #pragma unroll
    for (int e=0;e<ET;e++){
      float v=(acc[e]-mus[b+e])*scs[b+e]*lw+lb;
      hdn[e*256+c]=fmaxf(v,0.f);
    }
  }
  __syncthreads();

  // ---- layer 2 (k in regs; v partials via shuffle into vpart)
  float o[ET];
  if (kb){
    float bb = ldf<BF>(kb2,c);
    #pragma unroll
    for (int e=0;e<ET;e++) o[e]=bb;
    for (int j4=0;j4<32;j4++){
      float w0=ldf<BF>(kW2,(j4*4+0)*128+c);
      float w1=ldf<BF>(kW2,(j4*4+1)*128+c);
      float w2=ldf<BF>(kW2,(j4*4+2)*128+c);
      float w3=ldf<BF>(kW2,(j4*4+3)*128+c);
      #pragma unroll
      for (int e=0;e<ET;e++){
        float4 xv=*(const float4*)&hdn[e*256 + j4*4];
        o[e]=fmaf(w0,xv.x,o[e]); o[e]=fmaf(w1,xv.y,o[e]);
        o[e]=fmaf(w2,xv.z,o[e]); o[e]=fmaf(w3,xv.w,o[e]);
      }
    }
  } else {
    const int tv=c-128, cv=tv&15, jh=tv>>4;   // jh 0..7, 16 j's each
    #pragma unroll
    for (int e=0;e<ET;e++) o[e]=0.f;
    for (int jj=0;jj<16;jj++){
      float w = ldf<BF>(vW2, (jh*16+jj)*16 + cv);
      #pragma unroll
      for (int e=0;e<ET;e++)
        o[e]=fmaf(w, hdn[e*256 + 128 + jh*16 + jj], o[e]);
    }
    #pragma unroll
    for (int e=0;e<ET;e++){
      o[e]+=__shfl_xor(o[e],16);
      o[e]+=__shfl_xor(o[e],32);
    }
    if ((tv&48)==0){
      int half=tv>>6;
      #pragma unroll
      for (int e=0;e<ET;e++) vpart[half*256 + cv*16 + e]=o[e];
    }
  }
  __syncthreads();

  // ---- scores (k threads, shuffle-reduce over 8 dims) ; vs store (v threads)
  if (kb){
    const int h=c>>3;
    #pragma unroll
    for (int e=0;e<ET;e++){
      float p = qws[dste[e]*128 + c] * o[e];
      p += __shfl_xor(p,1); p += __shfl_xor(p,2); p += __shfl_xor(p,4);
      if ((c&7)==0){
        float s = p*0.35355339059327373f;
        scw[(e0+e)*16 + h] = s;
        atomicMax(&smx[dste[e]*16 + h], fmap(s));
      }
    }
  } else {
    const int tv=c-128;
    #pragma unroll
    for (int r=0;r<2;r++){
      int idx=r*128+tv; int e=idx>>4, hh=idx&15;
      float vs=(vpart[hh*16+e]+vpart[256+hh*16+e]+ldf<BF>(vb2,hh))*ewv[e];
      vsw[(e0+e)*16+hh]=vs;
    }
  }
}
__global__ void __launch_bounds__(256)
k_edge(const void* rfeat, const void* efeat, const int* ei,
       const void* ewW, const void* ewb,
       const void* kW1, const void* kb1, const void* klnw, const void* klnb,
       const void* kW2, const void* kb2,
       const void* vW1, const void* vb1, const void* vlnw, const void* vlnb,
       const void* vW2, const void* vb2,
       const float* hkd, const float* hks, const float* qws,
       float* scw, float* vsw, u32* smx, const int* flags){
  bool i64 = flags[1] != 0;
  if (flags[0]) edge_body<true >(rfeat,efeat,ei,i64,ewW,ewb,kW1,kb1,klnw,klnb,kW2,kb2,vW1,vb1,vlnw,vlnb,vW2,vb2,hkd,hks,qws,scw,vsw,smx);
  else          edge_body<false>(rfeat,efeat,ei,i64,ewW,ewb,kW1,kb1,klnw,klnb,kW2,kb2,vW1,vb1,vlnw,vlnb,vW2,vb2,hkd,hks,qws,scw,vsw,smx);
}

// ================= denom =================
__global__ void __launch_bounds__(256)
k_den(const int* ei, const u32* smx, const float* scw, float* den, const int* flags){
  int t = blockIdx.x*256 + threadIdx.x;
  bool i64 = flags[1] != 0;
  int e = t>>4, hh = t&15;
  int d = gidx(ei, EE + e, i64);
  float m  = funmap(smx[d*16 + hh]);
  atomicAdd(&den[d*16 + hh], expf(scw[t] - m));
}

// ================= alpha*vs reduce + scatter =================
__global__ void __launch_bounds__(256)
k_out(const int* ei, const void* relx, const float* scw, const float* vsw,
      const u32* smx, const float* den, float* oac, const int* flags){
  int t = blockIdx.x*256 + threadIdx.x;
  bool bf  = flags[0] != 0;
  bool i64 = flags[1] != 0;
  int e = t>>4, hh = t&15;
  int d = gidx(ei, EE + e, i64);
  float m = funmap(smx[d*16 + hh]);
  float a = expf(scw[t] - m) / den[d*16 + hh] * vsw[t];
  a += __shfl_xor(a, 8, 16);
  a += __shfl_xor(a, 4, 16);
  a += __shfl_xor(a, 2, 16);
  a += __shfl_xor(a, 1, 16);
  if (hh < 3){
    float r = bf ? __bfloat162float(((const __hip_bfloat16*)relx)[e*3+hh])
                 : ((const float*)relx)[e*3+hh];
    atomicAdd(&oac[d*3 + hh], a * r);
  }
}

// ================= finalize =================
__global__ void __launch_bounds__(256)
k_fin(const float* oac, void* dout, const int* flags){
  int t = blockIdx.x*256 + threadIdx.x;
  if (t >= NN*3) return;
  if (flags[0]) ((__hip_bfloat16*)dout)[t] = __float2bfloat16(oac[t]);
  else          ((float*)dout)[t] = oac[t];
}

extern "C" void kernel_launch(void* const* d_in, const int* in_sizes, int n_in,
                              void* d_out, int out_size, void* d_ws, size_t ws_size,
                              hipStream_t stream){
  const void* h     = d_in[0];
  const void* relx  = d_in[1];
  const void* rfeat = d_in[2];
  const void* efeat = d_in[3];
  const int*  ei    = (const int*)d_in[4];
  const void* ewW   = d_in[5];
  const void* ewb   = d_in[6];
  const void* kW1 = d_in[7],  *kb1 = d_in[8],  *klnw = d_in[9],  *klnb = d_in[10], *kW2 = d_in[11], *kb2 = d_in[12];
  const void* vW1 = d_in[13], *vb1 = d_in[14], *vlnw = d_in[15], *vlnb = d_in[16], *vW2 = d_in[17], *vb2 = d_in[18];
  const void* qW1 = d_in[19], *qb1 = d_in[20], *qlnw = d_in[21], *qlnb = d_in[22], *qW2 = d_in[23], *qb2 = d_in[24];

  float* qws = (float*)d_ws;                         // N*128
  float* hkd = qws + (size_t)NN*128;                 // N*256
  float* hks = hkd + (size_t)NN*256;                 // N*256
  float* scw = hks + (size_t)NN*256;                 // E*16
  float* vsw = scw + (size_t)EE*16;                  // E*16
  u32*   smx = (u32*)(vsw + (size_t)EE*16);          // N*16
  float* den = (float*)(smx + (size_t)NN*16);        // N*16
  float* oac = den + (size_t)NN*16;                  // N*3
  int* flags = (int*)(oac + (size_t)NN*3);           // 2 ints

  hipMemsetAsync(smx, 0, ((size_t)NN*16*2 + (size_t)NN*3)*sizeof(float), stream);
  k_detect<<<1, 64, 0, stream>>>((const u32*)klnw, (const u32*)ei, flags);
  k_node<<<NN/NT, 256, 0, stream>>>(h, kW1, vW1, hkd, hks, flags);
  k_q<<<NN/QT, 256, 0, stream>>>(h, qW1, qb1, qlnw, qlnb, qW2, qb2, qws, flags);
  k_edge<<<EE/ET, 256, 0, stream>>>(rfeat, efeat, ei, ewW, ewb,
                                    kW1,kb1,klnw,klnb,kW2,kb2,
                                    vW1,vb1,vlnw,vlnb,vW2,vb2,
                                    hkd, hks, qws, scw, vsw, smx, flags);
  k_den<<<(EE*16)/256, 256, 0, stream>>>(ei, smx, scw, den, flags);
  k_out<<<(EE*16)/256, 256, 0, stream>>>(ei, relx, scw, vsw, smx, den, oac, flags);
  k_fin<<<(NN*3 + 255)/256, 256, 0, stream>>>(oac, d_out, flags);
}

// Round 3
// 1272.283 us; speedup vs baseline: 2.3901x; 1.4915x over previous
//
#include <hip/hip_runtime.h>
#include <hip/hip_bf16.h>

#define NN 50000
#define EE 800000
#define ET 16   // edges per block in edge kernel
#define NT 16   // nodes per block in k_node
#define QT 8    // rows per block in k_q

typedef unsigned int u32;
typedef __attribute__((ext_vector_type(8))) short short8;
typedef __attribute__((ext_vector_type(4))) float floatx4;

// ---- ordered-uint mapping for float atomicMax ----
__device__ __forceinline__ u32 fmap(float x){
  u32 b = __float_as_uint(x);
  return (b & 0x80000000u) ? ~b : (b | 0x80000000u);
}
__device__ __forceinline__ float funmap(u32 u){
  u32 b = (u & 0x80000000u) ? (u ^ 0x80000000u) : ~u;
  return __uint_as_float(b);
}

// ---- dtype-hedged loads ----
template<bool BF>
__device__ __forceinline__ float ldf(const void* p, int i){
  if constexpr (BF) return __bfloat162float(((const __hip_bfloat16*)p)[i]);
  else              return ((const float*)p)[i];
}
__device__ __forceinline__ int gidx(const int* ei, int pos, bool i64){
  return i64 ? ei[2*pos] : ei[pos];
}

// ---- bf16 split helpers (RNE) ----
__device__ __forceinline__ unsigned short f2bf(float f){
  u32 u = __float_as_uint(f);
  u32 r = u + 0x7FFFu + ((u>>16)&1u);
  return (unsigned short)(r>>16);
}
__device__ __forceinline__ float bf2f(unsigned short s){
  return __uint_as_float(((u32)s)<<16);
}

__global__ void k_detect(const u32* lnw, const u32* ei, int* flags){
  if (threadIdx.x == 0){
    flags[0] = (lnw[0] == 0x3F803F80u) ? 1 : 0;
    flags[1] = ((ei[1] | ei[3] | ei[5] | ei[7]) == 0u) ? 1 : 0;
  }
}

// ================= weight prep: split to bf16 hi/lo, k-contiguous [n][k] =================
__global__ void __launch_bounds__(256)
k_wprep(const void* kW1, const void* vW1, const void* kW2, const void* vW2,
        unsigned short* w1sh, unsigned short* w1sl,
        unsigned short* w2kh, unsigned short* w2kl,
        unsigned short* w2vh, unsigned short* w2vl, const int* flags){
  int idx = blockIdx.x*256 + threadIdx.x;   // 0..16383
  bool bf = flags[0] != 0;
  if (idx < 16384){ int c = idx>>7, k = idx&127;
    float f = bf ? __bfloat162float(((const __hip_bfloat16*)kW2)[k*128+c]) : ((const float*)kW2)[k*128+c];
    unsigned short h = f2bf(f); w2kh[idx]=h; w2kl[idx]=f2bf(f - bf2f(h)); }
  if (idx < 2048){ int c = idx>>7, k = idx&127;
    float f = bf ? __bfloat162float(((const __hip_bfloat16*)vW2)[k*16+c]) : ((const float*)vW2)[k*16+c];
    unsigned short h = f2bf(f); w2vh[idx]=h; w2vl[idx]=f2bf(f - bf2f(h)); }
  if (idx < 8192){ int c = idx>>5, k = idx&31;
    float f = 0.f;
    if (k < 24){
      if (c < 128) f = bf ? __bfloat162float(((const __hip_bfloat16*)kW1)[k*128+c]) : ((const float*)kW1)[k*128+c];
      else         f = bf ? __bfloat162float(((const __hip_bfloat16*)vW1)[k*128+(c-128)]) : ((const float*)vW1)[k*128+(c-128)];
    }
    unsigned short h = f2bf(f); w1sh[idx]=h; w1sl[idx]=f2bf(f - bf2f(h)); }
}

// ================= node precompute: hkd = h @ W1[24:152], hks = h @ W1[152:280] =================
template<bool BF>
__device__ void node_body(const void* h, const void* kW1, const void* vW1,
                          float* hkd, float* hks){
  __shared__ float x[128*20];
  const int t  = threadIdx.x;
  const int n0 = blockIdx.x*NT;
  #pragma unroll
  for (int r=0;r<8;r++){ int idx=r*256+t; int n=idx>>7, j=idx&127;
    x[j*20+n] = ldf<BF>(h, (n0+n)*128 + j); }
  __syncthreads();
  const bool kb = (t < 128);
  const void* W = kb ? kW1 : vW1;
  const int  cc = kb ? t : t-128;
  float ad[NT], as[NT];
  #pragma unroll
  for (int e=0;e<NT;e++){ ad[e]=0.f; as[e]=0.f; }
  for (int j=0;j<128;j++){
    float wd = ldf<BF>(W, (24+j)*128 + cc);
    float ws = ldf<BF>(W, (152+j)*128 + cc);
    const float4* xr = (const float4*)&x[j*20];
    #pragma unroll
    for (int e4=0;e4<4;e4++){
      float4 xv = xr[e4];
      ad[e4*4+0]=fmaf(wd,xv.x,ad[e4*4+0]); as[e4*4+0]=fmaf(ws,xv.x,as[e4*4+0]);
      ad[e4*4+1]=fmaf(wd,xv.y,ad[e4*4+1]); as[e4*4+1]=fmaf(ws,xv.y,as[e4*4+1]);
      ad[e4*4+2]=fmaf(wd,xv.z,ad[e4*4+2]); as[e4*4+2]=fmaf(ws,xv.z,as[e4*4+2]);
      ad[e4*4+3]=fmaf(wd,xv.w,ad[e4*4+3]); as[e4*4+3]=fmaf(ws,xv.w,as[e4*4+3]);
    }
  }
  #pragma unroll
  for (int e=0;e<NT;e++){
    hkd[(n0+e)*256 + t] = ad[e];
    hks[(n0+e)*256 + t] = as[e];
  }
}
__global__ void __launch_bounds__(256)
k_node(const void* h, const void* kW1, const void* vW1, float* hkd, float* hks, const int* flags){
  if (flags[0]) node_body<true >(h,kW1,vW1,hkd,hks);
  else          node_body<false>(h,kW1,vW1,hkd,hks);
}

// ================= Q MLP: 8 rows per 256-thread block =================
template<bool BF>
__device__ void q_body(const void* h, const void* W1, const void* b1,
                       const void* lnw, const void* lnb,
                       const void* W2, const void* b2, float* qws){
  __shared__ float x[128*12];
  __shared__ float y[QT*128];
  __shared__ float2 redp[256];
  __shared__ float mus[QT], scs[QT];
  const int t = threadIdx.x, c = t&127, half = t>>7;
  const int n0 = blockIdx.x*QT;
  #pragma unroll
  for (int r=0;r<4;r++){ int idx=r*256+t; int n=idx>>7, j=idx&127;
    x[j*12+n] = ldf<BF>(h, (n0+n)*128 + j); }
  __syncthreads();
  float a[4];
  { float bb = ldf<BF>(b1,c);
    #pragma unroll
    for (int r=0;r<4;r++) a[r]=bb; }
  for (int j=0;j<128;j++){
    float w = ldf<BF>(W1, j*128+c);
    float4 xv = *(const float4*)&x[j*12 + half*4];
    a[0]=fmaf(w,xv.x,a[0]); a[1]=fmaf(w,xv.y,a[1]);
    a[2]=fmaf(w,xv.z,a[2]); a[3]=fmaf(w,xv.w,a[3]);
  }
  #pragma unroll
  for (int r=0;r<4;r++) y[(half*4+r)*128 + c] = a[r];
  __syncthreads();
  { int p=t>>5, l32=t&31;
    float s=0.f,s2=0.f;
    #pragma unroll
    for (int k=0;k<4;k++){ float v=y[p*128 + l32 + 32*k]; s+=v; s2=fmaf(v,v,s2); }
    redp[t]=make_float2(s,s2); }
  __syncthreads();
  if (t<QT){
    float s=0.f,s2=0.f;
    for (int i=0;i<32;i++){ float2 f=redp[t*32+i]; s+=f.x; s2+=f.y; }
    float mu=s*(1.f/128.f), var=s2*(1.f/128.f)-mu*mu;
    mus[t]=mu; scs[t]=rsqrtf(var+1e-5f);
  }
  __syncthreads();
  { float lw=ldf<BF>(lnw,c), lb=ldf<BF>(lnb,c);
    #pragma unroll
    for (int r=0;r<4;r++){ int row=half*4+r;
      float v=(a[r]-mus[row])*scs[row]*lw+lb;
      y[row*128+c]=fmaxf(v,0.f); } }
  __syncthreads();
  float o[4];
  { float bb=ldf<BF>(b2,c);
    #pragma unroll
    for (int r=0;r<4;r++) o[r]=bb; }
  for (int j4=0;j4<32;j4++){
    float w0=ldf<BF>(W2,(j4*4+0)*128+c);
    float w1=ldf<BF>(W2,(j4*4+1)*128+c);
    float w2=ldf<BF>(W2,(j4*4+2)*128+c);
    float w3=ldf<BF>(W2,(j4*4+3)*128+c);
    #pragma unroll
    for (int r=0;r<4;r++){
      float4 xv=*(const float4*)&y[(half*4+r)*128 + j4*4];
      o[r]=fmaf(w0,xv.x,o[r]); o[r]=fmaf(w1,xv.y,o[r]);
      o[r]=fmaf(w2,xv.z,o[r]); o[r]=fmaf(w3,xv.w,o[r]);
    }
  }
  #pragma unroll
  for (int r=0;r<4;r++) qws[(n0+half*4+r)*128 + c] = o[r];
}
__global__ void __launch_bounds__(256)
k_q(const void* h, const void* W1, const void* b1, const void* lnw, const void* lnb,
    const void* W2, const void* b2, float* qws, const int* flags){
  if (flags[0]) q_body<true >(h,W1,b1,lnw,lnb,W2,b2,qws);
  else          q_body<false>(h,W1,b1,lnw,lnb,W2,b2,qws);
}

// ================= Edge kernel (MFMA) =================
template<bool BF>
__device__ void edge_body(const void* rfeat, const void* efeat, const int* ei, bool i64,
                          const void* ewW, const void* ewb,
                          const void* kb1, const void* vb1,
                          const void* klnw, const void* klnb,
                          const void* vlnw, const void* vlnb,
                          const void* kb2, const void* vb2,
                          const unsigned short* w1sh, const unsigned short* w1sl,
                          const unsigned short* w2kh, const unsigned short* w2kl,
                          const unsigned short* w2vh, const unsigned short* w2vl,
                          const float* hkd, const float* hks, const float* qws,
                          float* scw, float* vsw, u32* smx){
  __shared__ float hdn[ET][260];             // pre-LN fp32; later reused as k_lds[16][132]
  __shared__ unsigned short ahi[ET*256];     // post-LN bf16 hi (XOR-swizzled)
  __shared__ unsigned short alo[ET*256];     // post-LN bf16 lo
  __shared__ unsigned short sfh[ET*32], sfl[ET*32];  // srf A hi/lo, [e][k] k<24 real
  __shared__ int   dste[ET], srce[ET];
  __shared__ float ewv[ET];
  __shared__ float2 redp[256];
  __shared__ float mus[32], scs[32];
  const int t  = threadIdx.x;
  const int e0 = blockIdx.x*ET;
  const int lane = t&63, w = t>>6;
  const int arow = lane&15, agrp = lane>>4;

  if (t < ET)        dste[t]    = gidx(ei, EE + e0 + t, i64);
  else if (t < 2*ET) srce[t-ET] = gidx(ei, e0 + (t-ET), i64);
  #pragma unroll
  for (int r=0;r<2;r++){ int idx=r*256+t; int e=idx>>5, j=idx&31;
    float f = (j<4) ? ldf<BF>(efeat,(e0+e)*4+j)
            : (j<24 ? ldf<BF>(rfeat,(e0+e)*20+(j-4)) : 0.f);
    unsigned short hh=f2bf(f); sfh[idx]=hh; sfl[idx]=f2bf(f-bf2f(hh));
  }
  __syncthreads();   // S1: indices + srf staged

  if (t < ET){
    float aw = ldf<BF>(ewb, 0);
    #pragma unroll
    for (int j=0;j<20;j++) aw = fmaf(ldf<BF>(rfeat,(e0+t)*20+j), ldf<BF>(ewW,j), aw);
    ewv[t] = (1.f/(1.f + expf(-aw))) * (1.f/16.f);
  }
  { float b1c = (t<128) ? ldf<BF>(kb1,t) : ldf<BF>(vb1,t-128);
    float gd[ET], gs[ET];
    #pragma unroll
    for (int e=0;e<ET;e++) gd[e] = hkd[(size_t)dste[e]*256 + t];
    #pragma unroll
    for (int e=0;e<ET;e++) gs[e] = hks[(size_t)srce[e]*256 + t];
    #pragma unroll
    for (int e=0;e<ET;e++) hdn[e][t] = gd[e] + gs[e] + b1c;
  }
  __syncthreads();   // S2: hdn gather-part + ewv ready

  // ---- srf MFMA: hdn += srf[16x32] @ w1s[32x256] (bf16x3)
  { short8 Ah = *(const short8*)&sfh[arow*32 + agrp*8];
    short8 Al = *(const short8*)&sfl[arow*32 + agrp*8];
    #pragma unroll
    for (int nt=0; nt<4; nt++){
      int col = w*64 + nt*16 + (lane&15);
      floatx4 C;
      #pragma unroll
      for (int r=0;r<4;r++) C[r] = hdn[agrp*4+r][col];
      short8 Bh = *(const short8*)&w1sh[col*32 + agrp*8];
      short8 Bl = *(const short8*)&w1sl[col*32 + agrp*8];
      C = __builtin_amdgcn_mfma_f32_16x16x32_bf16(Ah, Bh, C, 0,0,0);
      C = __builtin_amdgcn_mfma_f32_16x16x32_bf16(Al, Bh, C, 0,0,0);
      C = __builtin_amdgcn_mfma_f32_16x16x32_bf16(Ah, Bl, C, 0,0,0);
      #pragma unroll
      for (int r=0;r<4;r++) hdn[agrp*4+r][col] = C[r];
    }
  }
  __syncthreads();   // S3: full pre-LN hidden ready

  // ---- LayerNorm + ReLU + bf16 hi/lo split into swizzled A buffers
  { float acc[ET];
    #pragma unroll
    for (int e=0;e<ET;e++) acc[e] = hdn[e][t];
    { int p=t>>3, l8=t&7, b=p>>4, eidx=p&15;
      float s=0.f, s2=0.f;
      #pragma unroll
      for (int k=0;k<16;k++){ float v=hdn[eidx][b*128 + l8 + 8*k]; s+=v; s2=fmaf(v,v,s2); }
      redp[t]=make_float2(s,s2);
    }
    __syncthreads();
    if (t<32){ float s=0.f,s2=0.f;
      #pragma unroll
      for (int k=0;k<8;k++){ float2 f=redp[t*8+k]; s+=f.x; s2+=f.y; }
      float mu=s*(1.f/128.f), var=s2*(1.f/128.f)-mu*mu;
      mus[t]=mu; scs[t]=rsqrtf(var+1e-5f);
    }
    __syncthreads();
    { bool kb=(t<128); int cc=kb?t:t-128;
      float lw = kb?ldf<BF>(klnw,cc):ldf<BF>(vlnw,cc);
      float lb = kb?ldf<BF>(klnb,cc):ldf<BF>(vlnb,cc);
      int bo = kb?0:16;
      #pragma unroll
      for (int e=0;e<ET;e++){
        float v=(acc[e]-mus[bo+e])*scs[bo+e]*lw+lb;
        v=fmaxf(v,0.f);
        unsigned short hh=f2bf(v);
        unsigned short ll=f2bf(v-bf2f(hh));
        int idx=(e*256+t)^((e&7)<<3);
        ahi[idx]=hh; alo[idx]=ll;
      }
    }
  }
  __syncthreads();   // S4: A buffers ready; hdn free

  // ---- layer 2 MFMA: k [16x128]@[128x128] across 4 waves (2 n-tiles each); v on wave 3
  float* hl = &hdn[0][0];
  { const int colb = lane&15;
    const int c0 = (2*w+0)*16 + colb;
    const int c1 = (2*w+1)*16 + colb;
    floatx4 Ck0, Ck1, Cv;
    { float b0=ldf<BF>(kb2,c0), b1v=ldf<BF>(kb2,c1);
      #pragma unroll
      for (int r=0;r<4;r++){ Ck0[r]=b0; Ck1[r]=b1v; } }
    const bool dv = (w==3);
    if (dv){ float bv=ldf<BF>(vb2,colb);
      #pragma unroll
      for (int r=0;r<4;r++) Cv[r]=bv; }
    #pragma unroll
    for (int ks=0; ks<4; ks++){
      int aidx = (arow*256 + ks*32 + agrp*8) ^ ((arow&7)<<3);
      short8 Ah = *(const short8*)&ahi[aidx];
      short8 Al = *(const short8*)&alo[aidx];
      { short8 Bh = *(const short8*)&w2kh[c0*128 + ks*32 + agrp*8];
        short8 Bl = *(const short8*)&w2kl[c0*128 + ks*32 + agrp*8];
        Ck0 = __builtin_amdgcn_mfma_f32_16x16x32_bf16(Ah, Bh, Ck0, 0,0,0);
        Ck0 = __builtin_amdgcn_mfma_f32_16x16x32_bf16(Al, Bh, Ck0, 0,0,0);
        Ck0 = __builtin_amdgcn_mfma_f32_16x16x32_bf16(Ah, Bl, Ck0, 0,0,0); }
      { short8 Bh = *(const short8*)&w2kh[c1*128 + ks*32 + agrp*8];
        short8 Bl = *(const short8*)&w2kl[c1*128 + ks*32 + agrp*8];
        Ck1 = __builtin_amdgcn_mfma_f32_16x16x32_bf16(Ah, Bh, Ck1, 0,0,0);
        Ck1 = __builtin_amdgcn_mfma_f32_16x16x32_bf16(Al, Bh, Ck1, 0,0,0);
        Ck1 = __builtin_amdgcn_mfma_f32_16x16x32_bf16(Ah, Bl, Ck1, 0,0,0); }
      if (dv){
        int avidx = (arow*256 + 128 + ks*32 + agrp*8) ^ ((arow&7)<<3);
        short8 Avh = *(const short8*)&ahi[avidx];
        short8 Avl = *(const short8*)&alo[avidx];
        short8 Bh = *(const short8*)&w2vh[colb*128 + ks*32 + agrp*8];
        short8 Bl = *(const short8*)&w2vl[colb*128 + ks*32 + agrp*8];
        Cv = __builtin_amdgcn_mfma_f32_16x16x32_bf16(Avh, Bh, Cv, 0,0,0);
        Cv = __builtin_amdgcn_mfma_f32_16x16x32_bf16(Avl, Bh, Cv, 0,0,0);
        Cv = __builtin_amdgcn_mfma_f32_16x16x32_bf16(Avh, Bl, Cv, 0,0,0);
      }
    }
    #pragma unroll
    for (int r=0;r<4;r++){
      int row = agrp*4 + r;
      hl[row*132 + c0] = Ck0[r];
      hl[row*132 + c1] = Ck1[r];
    }
    if (dv){
      #pragma unroll
      for (int r=0;r<4;r++){ int row = agrp*4 + r;
        vsw[(size_t)(e0+row)*16 + colb] = Cv[r]*ewv[row]; }
    }
  }
  __syncthreads();   // S5: k in hl, vsw written

  // ---- scores + segment max
  { int e=t>>4, hh=t&15, d=dste[e];
    const float* qr = qws + (size_t)d*128 + hh*8;
    float4 q0=*(const float4*)qr, q1=*(const float4*)(qr+4);
    const float* kr = hl + e*132 + hh*8;
    float4 k0=*(const float4*)kr, k1=*(const float4*)(kr+4);
    float s = q0.x*k0.x+q0.y*k0.y+q0.z*k0.z+q0.w*k0.w
            + q1.x*k1.x+q1.y*k1.y+q1.z*k1.z+q1.w*k1.w;
    s *= 0.35355339059327373f;
    scw[(size_t)(e0+e)*16 + hh] = s;
    atomicMax(&smx[d*16 + hh], fmap(s));
  }
}
__global__ void __launch_bounds__(256)
k_edge(const void* rfeat, const void* efeat, const int* ei,
       const void* ewW, const void* ewb,
       const void* kb1, const void* vb1,
       const void* klnw, const void* klnb, const void* vlnw, const void* vlnb,
       const void* kb2, const void* vb2,
       const unsigned short* w1sh, const unsigned short* w1sl,
       const unsigned short* w2kh, const unsigned short* w2kl,
       const unsigned short* w2vh, const unsigned short* w2vl,
       const float* hkd, const float* hks, const float* qws,
       float* scw, float* vsw, u32* smx, const int* flags){
  bool i64 = flags[1] != 0;
  if (flags[0]) edge_body<true >(rfeat,efeat,ei,i64,ewW,ewb,kb1,vb1,klnw,klnb,vlnw,vlnb,kb2,vb2,
                                 w1sh,w1sl,w2kh,w2kl,w2vh,w2vl,hkd,hks,qws,scw,vsw,smx);
  else          edge_body<false>(rfeat,efeat,ei,i64,ewW,ewb,kb1,vb1,klnw,klnb,vlnw,vlnb,kb2,vb2,
                                 w1sh,w1sl,w2kh,w2kl,w2vh,w2vl,hkd,hks,qws,scw,vsw,smx);
}

// ================= denom =================
__global__ void __launch_bounds__(256)
k_den(const int* ei, const u32* smx, const float* scw, float* den, const int* flags){
  int t = blockIdx.x*256 + threadIdx.x;
  bool i64 = flags[1] != 0;
  int e = t>>4, hh = t&15;
  int d = gidx(ei, EE + e, i64);
  float m  = funmap(smx[d*16 + hh]);
  atomicAdd(&den[d*16 + hh], expf(scw[t] - m));
}

// ================= alpha*vs reduce + scatter =================
__global__ void __launch_bounds__(256)
k_out(const int* ei, const void* relx, const float* scw, const float* vsw,
      const u32* smx, const float* den, float* oac, const int* flags){
  int t = blockIdx.x*256 + threadIdx.x;
  bool bf  = flags[0] != 0;
  bool i64 = flags[1] != 0;
  int e = t>>4, hh = t&15;
  int d = gidx(ei, EE + e, i64);
  float m = funmap(smx[d*16 + hh]);
  float a = expf(scw[t] - m) / den[d*16 + hh] * vsw[t];
  a += __shfl_xor(a, 8, 16);
  a += __shfl_xor(a, 4, 16);
  a += __shfl_xor(a, 2, 16);
  a += __shfl_xor(a, 1, 16);
  if (hh < 3){
    float r = bf ? __bfloat162float(((const __hip_bfloat16*)relx)[e*3+hh])
                 : ((const float*)relx)[e*3+hh];
    atomicAdd(&oac[d*3 + hh], a * r);
  }
}

// ================= finalize =================
__global__ void __launch_bounds__(256)
k_fin(const float* oac, void* dout, const int* flags){
  int t = blockIdx.x*256 + threadIdx.x;
  if (t >= NN*3) return;
  if (flags[0]) ((__hip_bfloat16*)dout)[t] = __float2bfloat16(oac[t]);
  else          ((float*)dout)[t] = oac[t];
}

extern "C" void kernel_launch(void* const* d_in, const int* in_sizes, int n_in,
                              void* d_out, int out_size, void* d_ws, size_t ws_size,
                              hipStream_t stream){
  const void* h     = d_in[0];
  const void* relx  = d_in[1];
  const void* rfeat = d_in[2];
  const void* efeat = d_in[3];
  const int*  ei    = (const int*)d_in[4];
  const void* ewW   = d_in[5];
  const void* ewb   = d_in[6];
  const void* kW1 = d_in[7],  *kb1 = d_in[8],  *klnw = d_in[9],  *klnb = d_in[10], *kW2 = d_in[11], *kb2 = d_in[12];
  const void* vW1 = d_in[13], *vb1 = d_in[14], *vlnw = d_in[15], *vlnb = d_in[16], *vW2 = d_in[17], *vb2 = d_in[18];
  const void* qW1 = d_in[19], *qb1 = d_in[20], *qlnw = d_in[21], *qlnb = d_in[22], *qW2 = d_in[23], *qb2 = d_in[24];

  float* qws = (float*)d_ws;                         // N*128
  float* hkd = qws + (size_t)NN*128;                 // N*256
  float* hks = hkd + (size_t)NN*256;                 // N*256
  float* scw = hks + (size_t)NN*256;                 // E*16
  float* vsw = scw + (size_t)EE*16;                  // E*16
  u32*   smx = (u32*)(vsw + (size_t)EE*16);          // N*16
  float* den = (float*)(smx + (size_t)NN*16);        // N*16
  float* oac = den + (size_t)NN*16;                  // N*3
  unsigned short* w1sh = (unsigned short*)(oac + (size_t)NN*3);  // 8192
  unsigned short* w1sl = w1sh + 8192;
  unsigned short* w2kh = w1sl + 8192;                // 16384
  unsigned short* w2kl = w2kh + 16384;
  unsigned short* w2vh = w2kl + 16384;               // 2048
  unsigned short* w2vl = w2vh + 2048;
  int* flags = (int*)(w2vl + 2048);                  // 2 ints

  hipMemsetAsync(smx, 0, ((size_t)NN*16*2 + (size_t)NN*3)*sizeof(float), stream);
  k_detect<<<1, 64, 0, stream>>>((const u32*)klnw, (const u32*)ei, flags);
  k_wprep<<<64, 256, 0, stream>>>(kW1, vW1, kW2, vW2, w1sh, w1sl, w2kh, w2kl, w2vh, w2vl, flags);
  k_node<<<NN/NT, 256, 0, stream>>>(h, kW1, vW1, hkd, hks, flags);
  k_q<<<NN/QT, 256, 0, stream>>>(h, qW1, qb1, qlnw, qlnb, qW2, qb2, qws, flags);
  k_edge<<<EE/ET, 256, 0, stream>>>(rfeat, efeat, ei, ewW, ewb,
                                    kb1, vb1, klnw, klnb, vlnw, vlnb, kb2, vb2,
                                    w1sh, w1sl, w2kh, w2kl, w2vh, w2vl,
                                    hkd, hks, qws, scw, vsw, smx, flags);
  k_den<<<(EE*16)/256, 256, 0, stream>>>(ei, smx, scw, den, flags);
  k_out<<<(EE*16)/256, 256, 0, stream>>>(ei, relx, scw, vsw, smx, den, oac, flags);
  k_fin<<<(NN*3 + 255)/256, 256, 0, stream>>>(oac, d_out, flags);
}

// Round 4
// 1000.181 us; speedup vs baseline: 3.0403x; 1.2721x over previous
//
#include <hip/hip_runtime.h>
#include <hip/hip_bf16.h>

#define NN 50000
#define EE 800000
#define ET 16   // edges per block in edge kernel
#define NT 16   // nodes per block in k_node
#define QT 8    // rows per block in k_q

typedef unsigned int u32;
typedef __attribute__((ext_vector_type(8))) short short8;
typedef __attribute__((ext_vector_type(4))) float floatx4;

__device__ __forceinline__ u32 fmap(float x){
  u32 b = __float_as_uint(x);
  return (b & 0x80000000u) ? ~b : (b | 0x80000000u);
}
__device__ __forceinline__ float funmap(u32 u){
  u32 b = (u & 0x80000000u) ? (u ^ 0x80000000u) : ~u;
  return __uint_as_float(b);
}

template<bool BF>
__device__ __forceinline__ float ldf(const void* p, int i){
  if constexpr (BF) return __bfloat162float(((const __hip_bfloat16*)p)[i]);
  else              return ((const float*)p)[i];
}
__device__ __forceinline__ int gidx(const int* ei, int pos, bool i64){
  return i64 ? ei[2*pos] : ei[pos];
}

__device__ __forceinline__ unsigned short f2bf(float f){
  u32 u = __float_as_uint(f);
  u32 r = u + 0x7FFFu + ((u>>16)&1u);
  return (unsigned short)(r>>16);
}
__device__ __forceinline__ float bf2f(unsigned short s){
  return __uint_as_float(((u32)s)<<16);
}

__global__ void k_detect(const u32* lnw, const u32* ei, int* flags){
  if (threadIdx.x == 0){
    flags[0] = (lnw[0] == 0x3F803F80u) ? 1 : 0;
    flags[1] = ((ei[1] | ei[3] | ei[5] | ei[7]) == 0u) ? 1 : 0;
  }
}

// ================= weight prep: split to bf16 hi/lo, k-contiguous [n][k] =================
__global__ void __launch_bounds__(256)
k_wprep(const void* kW1, const void* vW1, const void* kW2, const void* vW2,
        unsigned short* w1sh, unsigned short* w1sl,
        unsigned short* w2kh, unsigned short* w2kl,
        unsigned short* w2vh, unsigned short* w2vl, const int* flags){
  int idx = blockIdx.x*256 + threadIdx.x;
  bool bf = flags[0] != 0;
  if (idx < 16384){ int c = idx>>7, k = idx&127;
    float f = bf ? __bfloat162float(((const __hip_bfloat16*)kW2)[k*128+c]) : ((const float*)kW2)[k*128+c];
    unsigned short h = f2bf(f); w2kh[idx]=h; w2kl[idx]=f2bf(f - bf2f(h)); }
  if (idx < 2048){ int c = idx>>7, k = idx&127;
    float f = bf ? __bfloat162float(((const __hip_bfloat16*)vW2)[k*16+c]) : ((const float*)vW2)[k*16+c];
    unsigned short h = f2bf(f); w2vh[idx]=h; w2vl[idx]=f2bf(f - bf2f(h)); }
  if (idx < 8192){ int c = idx>>5, k = idx&31;
    float f = 0.f;
    if (k < 24){
      if (c < 128) f = bf ? __bfloat162float(((const __hip_bfloat16*)kW1)[k*128+c]) : ((const float*)kW1)[k*128+c];
      else         f = bf ? __bfloat162float(((const __hip_bfloat16*)vW1)[k*128+(c-128)]) : ((const float*)vW1)[k*128+(c-128)];
    }
    unsigned short h = f2bf(f); w1sh[idx]=h; w1sl[idx]=f2bf(f - bf2f(h)); }
}

// ================= node precompute =================
template<bool BF>
__device__ void node_body(const void* h, const void* kW1, const void* vW1,
                          float* hkd, float* hks, float* x){
  const int t  = threadIdx.x;
  const int n0 = blockIdx.x*NT;
  #pragma unroll
  for (int r=0;r<8;r++){ int idx=r*256+t; int n=idx>>7, j=idx&127;
    x[j*20+n] = ldf<BF>(h, (n0+n)*128 + j); }
  __syncthreads();
  const bool kb = (t < 128);
  const void* W = kb ? kW1 : vW1;
  const int  cc = kb ? t : t-128;
  float ad[NT], as[NT];
  #pragma unroll
  for (int e=0;e<NT;e++){ ad[e]=0.f; as[e]=0.f; }
  for (int j=0;j<128;j++){
    float wd = ldf<BF>(W, (24+j)*128 + cc);
    float ws = ldf<BF>(W, (152+j)*128 + cc);
    const float4* xr = (const float4*)&x[j*20];
    #pragma unroll
    for (int e4=0;e4<4;e4++){
      float4 xv = xr[e4];
      ad[e4*4+0]=fmaf(wd,xv.x,ad[e4*4+0]); as[e4*4+0]=fmaf(ws,xv.x,as[e4*4+0]);
      ad[e4*4+1]=fmaf(wd,xv.y,ad[e4*4+1]); as[e4*4+1]=fmaf(ws,xv.y,as[e4*4+1]);
      ad[e4*4+2]=fmaf(wd,xv.z,ad[e4*4+2]); as[e4*4+2]=fmaf(ws,xv.z,as[e4*4+2]);
      ad[e4*4+3]=fmaf(wd,xv.w,ad[e4*4+3]); as[e4*4+3]=fmaf(ws,xv.w,as[e4*4+3]);
    }
  }
  #pragma unroll
  for (int e=0;e<NT;e++){
    hkd[(n0+e)*256 + t] = ad[e];
    hks[(n0+e)*256 + t] = as[e];
  }
}
__global__ void __launch_bounds__(256)
k_node(const void* h, const void* kW1, const void* vW1, float* hkd, float* hks, const int* flags){
  __shared__ float x[128*20];
  if (flags[0]) node_body<true >(h,kW1,vW1,hkd,hks,x);
  else          node_body<false>(h,kW1,vW1,hkd,hks,x);
}

// ================= Q MLP =================
template<bool BF>
__device__ void q_body(const void* h, const void* W1, const void* b1,
                       const void* lnw, const void* lnb,
                       const void* W2, const void* b2, float* qws,
                       float* x, float* y, float2* redp, float* mus, float* scs){
  const int t = threadIdx.x, c = t&127, half = t>>7;
  const int n0 = blockIdx.x*QT;
  #pragma unroll
  for (int r=0;r<4;r++){ int idx=r*256+t; int n=idx>>7, j=idx&127;
    x[j*12+n] = ldf<BF>(h, (n0+n)*128 + j); }
  __syncthreads();
  float a[4];
  { float bb = ldf<BF>(b1,c);
    #pragma unroll
    for (int r=0;r<4;r++) a[r]=bb; }
  for (int j=0;j<128;j++){
    float w = ldf<BF>(W1, j*128+c);
    float4 xv = *(const float4*)&x[j*12 + half*4];
    a[0]=fmaf(w,xv.x,a[0]); a[1]=fmaf(w,xv.y,a[1]);
    a[2]=fmaf(w,xv.z,a[2]); a[3]=fmaf(w,xv.w,a[3]);
  }
  #pragma unroll
  for (int r=0;r<4;r++) y[(half*4+r)*128 + c] = a[r];
  __syncthreads();
  { int p=t>>5, l32=t&31;
    float s=0.f,s2=0.f;
    #pragma unroll
    for (int k=0;k<4;k++){ float v=y[p*128 + l32 + 32*k]; s+=v; s2=fmaf(v,v,s2); }
    redp[t]=make_float2(s,s2); }
  __syncthreads();
  if (t<QT){
    float s=0.f,s2=0.f;
    for (int i=0;i<32;i++){ float2 f=redp[t*32+i]; s+=f.x; s2+=f.y; }
    float mu=s*(1.f/128.f), var=s2*(1.f/128.f)-mu*mu;
    mus[t]=mu; scs[t]=rsqrtf(var+1e-5f);
  }
  __syncthreads();
  { float lw=ldf<BF>(lnw,c), lb=ldf<BF>(lnb,c);
    #pragma unroll
    for (int r=0;r<4;r++){ int row=half*4+r;
      float v=(a[r]-mus[row])*scs[row]*lw+lb;
      y[row*128+c]=fmaxf(v,0.f); } }
  __syncthreads();
  float o[4];
  { float bb=ldf<BF>(b2,c);
    #pragma unroll
    for (int r=0;r<4;r++) o[r]=bb; }
  for (int j4=0;j4<32;j4++){
    float w0=ldf<BF>(W2,(j4*4+0)*128+c);
    float w1=ldf<BF>(W2,(j4*4+1)*128+c);
    float w2=ldf<BF>(W2,(j4*4+2)*128+c);
    float w3=ldf<BF>(W2,(j4*4+3)*128+c);
    #pragma unroll
    for (int r=0;r<4;r++){
      float4 xv=*(const float4*)&y[(half*4+r)*128 + j4*4];
      o[r]=fmaf(w0,xv.x,o[r]); o[r]=fmaf(w1,xv.y,o[r]);
      o[r]=fmaf(w2,xv.z,o[r]); o[r]=fmaf(w3,xv.w,o[r]);
    }
  }
  #pragma unroll
  for (int r=0;r<4;r++) qws[(n0+half*4+r)*128 + c] = o[r];
}
__global__ void __launch_bounds__(256)
k_q(const void* h, const void* W1, const void* b1, const void* lnw, const void* lnb,
    const void* W2, const void* b2, float* qws, const int* flags){
  __shared__ float x[128*12];
  __shared__ float y[QT*128];
  __shared__ float2 redp[256];
  __shared__ float mus[QT], scs[QT];
  if (flags[0]) q_body<true >(h,W1,b1,lnw,lnb,W2,b2,qws,x,y,redp,mus,scs);
  else          q_body<false>(h,W1,b1,lnw,lnb,W2,b2,qws,x,y,redp,mus,scs);
}

// ================= Edge kernel (MFMA) =================
template<bool BF>
__device__ void edge_body(const void* rfeat, const void* efeat, const int* ei, bool i64,
                          const void* ewW, const void* ewb,
                          const void* kb1, const void* vb1,
                          const void* klnw, const void* klnb,
                          const void* vlnw, const void* vlnb,
                          const void* kb2, const void* vb2,
                          const unsigned short* w1sh, const unsigned short* w1sl,
                          const unsigned short* w2kh, const unsigned short* w2kl,
                          const unsigned short* w2vh, const unsigned short* w2vl,
                          const float* hkd, const float* hks, const float* qws,
                          float* scw, float* vsw, u32* smx,
                          float (*hdn)[260], unsigned short* ahi, unsigned short* alo,
                          unsigned short* sfh, unsigned short* sfl,
                          int* dste, int* srce, float* ewv,
                          float2* redp, float* mus, float* scs){
  const int t  = threadIdx.x;
  const int e0 = blockIdx.x*ET;
  const int lane = t&63, w = t>>6;
  const int arow = lane&15, agrp = lane>>4;

  if (t < ET)        dste[t]    = gidx(ei, EE + e0 + t, i64);
  else if (t < 2*ET) srce[t-ET] = gidx(ei, e0 + (t-ET), i64);
  #pragma unroll
  for (int r=0;r<2;r++){ int idx=r*256+t; int e=idx>>5, j=idx&31;
    float f = (j<4) ? ldf<BF>(efeat,(e0+e)*4+j)
            : (j<24 ? ldf<BF>(rfeat,(e0+e)*20+(j-4)) : 0.f);
    unsigned short hh=f2bf(f); sfh[idx]=hh; sfl[idx]=f2bf(f-bf2f(hh));
  }
  __syncthreads();   // S1: indices + srf staged

  if (t < ET){
    float aw = ldf<BF>(ewb, 0);
    #pragma unroll
    for (int j=0;j<20;j++) aw = fmaf(ldf<BF>(rfeat,(e0+t)*20+j), ldf<BF>(ewW,j), aw);
    ewv[t] = (1.f/(1.f + expf(-aw))) * (1.f/16.f);
  }
  // ---- gather hkd/hks via float4: wave w -> edges 4w..4w+3, lane -> cols 4l..4l+3
  { float bb[4];
    #pragma unroll
    for (int j=0;j<4;j++){ int col=4*lane+j;
      bb[j] = (col<128) ? ldf<BF>(kb1,col) : ldf<BF>(vb1,col-128); }
    #pragma unroll
    for (int r=0;r<4;r++){
      int e = w*4 + r;
      float4 gd = *(const float4*)&hkd[(size_t)dste[e]*256 + 4*lane];
      float4 gs = *(const float4*)&hks[(size_t)srce[e]*256 + 4*lane];
      float4 hv;
      hv.x = gd.x+gs.x+bb[0]; hv.y = gd.y+gs.y+bb[1];
      hv.z = gd.z+gs.z+bb[2]; hv.w = gd.w+gs.w+bb[3];
      *(float4*)&hdn[e][4*lane] = hv;
    }
  }
  __syncthreads();   // S2: hdn gather-part + ewv ready

  // ---- srf MFMA: hdn += srf[16x32] @ w1s[32x256] (bf16x3)
  { short8 Ah = *(const short8*)&sfh[arow*32 + agrp*8];
    short8 Al = *(const short8*)&sfl[arow*32 + agrp*8];
    #pragma unroll
    for (int nt=0; nt<4; nt++){
      int col = w*64 + nt*16 + arow;
      floatx4 C;
      #pragma unroll
      for (int r=0;r<4;r++) C[r] = hdn[agrp*4+r][col];
      short8 Bh = *(const short8*)&w1sh[col*32 + agrp*8];
      short8 Bl = *(const short8*)&w1sl[col*32 + agrp*8];
      C = __builtin_amdgcn_mfma_f32_16x16x32_bf16(Ah, Bh, C, 0,0,0);
      C = __builtin_amdgcn_mfma_f32_16x16x32_bf16(Al, Bh, C, 0,0,0);
      C = __builtin_amdgcn_mfma_f32_16x16x32_bf16(Ah, Bl, C, 0,0,0);
      #pragma unroll
      for (int r=0;r<4;r++) hdn[agrp*4+r][col] = C[r];
    }
  }
  __syncthreads();   // S3: full pre-LN hidden ready

  // ---- LayerNorm + ReLU + bf16 hi/lo split into swizzled A buffers
  { float acc[ET];
    #pragma unroll
    for (int e=0;e<ET;e++) acc[e] = hdn[e][t];
    { int p=t>>3, l8=t&7, b=p>>4, eidx=p&15;
      float s=0.f, s2=0.f;
      #pragma unroll
      for (int k=0;k<16;k++){ float v=hdn[eidx][b*128 + l8 + 8*k]; s+=v; s2=fmaf(v,v,s2); }
      redp[t]=make_float2(s,s2);
    }
    __syncthreads();
    if (t<32){ float s=0.f,s2=0.f;
      #pragma unroll
      for (int k=0;k<8;k++){ float2 f=redp[t*8+k]; s+=f.x; s2+=f.y; }
      float mu=s*(1.f/128.f), var=s2*(1.f/128.f)-mu*mu;
      mus[t]=mu; scs[t]=rsqrtf(var+1e-5f);
    }
    __syncthreads();
    { bool kb=(t<128); int cc=kb?t:t-128;
      float lw = kb?ldf<BF>(klnw,cc):ldf<BF>(vlnw,cc);
      float lb = kb?ldf<BF>(klnb,cc):ldf<BF>(vlnb,cc);
      int bo = kb?0:16;
      #pragma unroll
      for (int e=0;e<ET;e++){
        float v=(acc[e]-mus[bo+e])*scs[bo+e]*lw+lb;
        v=fmaxf(v,0.f);
        unsigned short hh=f2bf(v);
        unsigned short ll=f2bf(v-bf2f(hh));
        int idx=(e*256+t)^((e&7)<<3);
        ahi[idx]=hh; alo[idx]=ll;
      }
    }
  }
  __syncthreads();   // S4: A buffers ready; hdn free

  // ---- layer 2 MFMA
  float* hl = &hdn[0][0];
  { const int colb = arow;
    const int c0 = (2*w+0)*16 + colb;
    const int c1 = (2*w+1)*16 + colb;
    floatx4 Ck0, Ck1, Cv;
    { float b0=ldf<BF>(kb2,c0), b1v=ldf<BF>(kb2,c1);
      #pragma unroll
      for (int r=0;r<4;r++){ Ck0[r]=b0; Ck1[r]=b1v; } }
    const bool dv = (w==3);
    if (dv){ float bv=ldf<BF>(vb2,colb);
      #pragma unroll
      for (int r=0;r<4;r++) Cv[r]=bv; }
    #pragma unroll
    for (int ks=0; ks<4; ks++){
      int aidx = (arow*256 + ks*32 + agrp*8) ^ ((arow&7)<<3);
      short8 Ah = *(const short8*)&ahi[aidx];
      short8 Al = *(const short8*)&alo[aidx];
      { short8 Bh = *(const short8*)&w2kh[c0*128 + ks*32 + agrp*8];
        short8 Bl = *(const short8*)&w2kl[c0*128 + ks*32 + agrp*8];
        Ck0 = __builtin_amdgcn_mfma_f32_16x16x32_bf16(Ah, Bh, Ck0, 0,0,0);
        Ck0 = __builtin_amdgcn_mfma_f32_16x16x32_bf16(Al, Bh, Ck0, 0,0,0);
        Ck0 = __builtin_amdgcn_mfma_f32_16x16x32_bf16(Ah, Bl, Ck0, 0,0,0); }
      { short8 Bh = *(const short8*)&w2kh[c1*128 + ks*32 + agrp*8];
        short8 Bl = *(const short8*)&w2kl[c1*128 + ks*32 + agrp*8];
        Ck1 = __builtin_amdgcn_mfma_f32_16x16x32_bf16(Ah, Bh, Ck1, 0,0,0);
        Ck1 = __builtin_amdgcn_mfma_f32_16x16x32_bf16(Al, Bh, Ck1, 0,0,0);
        Ck1 = __builtin_amdgcn_mfma_f32_16x16x32_bf16(Ah, Bl, Ck1, 0,0,0); }
      if (dv){
        int avidx = (arow*256 + 128 + ks*32 + agrp*8) ^ ((arow&7)<<3);
        short8 Avh = *(const short8*)&ahi[avidx];
        short8 Avl = *(const short8*)&alo[avidx];
        short8 Bh = *(const short8*)&w2vh[colb*128 + ks*32 + agrp*8];
        short8 Bl = *(const short8*)&w2vl[colb*128 + ks*32 + agrp*8];
        Cv = __builtin_amdgcn_mfma_f32_16x16x32_bf16(Avh, Bh, Cv, 0,0,0);
        Cv = __builtin_amdgcn_mfma_f32_16x16x32_bf16(Avl, Bh, Cv, 0,0,0);
        Cv = __builtin_amdgcn_mfma_f32_16x16x32_bf16(Avh, Bl, Cv, 0,0,0);
      }
    }
    #pragma unroll
    for (int r=0;r<4;r++){
      int row = agrp*4 + r;
      hl[row*132 + c0] = Ck0[r];
      hl[row*132 + c1] = Ck1[r];
    }
    if (dv){
      #pragma unroll
      for (int r=0;r<4;r++){ int row = agrp*4 + r;
        vsw[(size_t)(e0+row)*16 + colb] = Cv[r]*ewv[row]; }
    }
  }
  __syncthreads();   // S5: k in hl, vsw written

  // ---- scores + segment max
  { int e=t>>4, hh=t&15, d=dste[e];
    const float* qr = qws + (size_t)d*128 + hh*8;
    float4 q0=*(const float4*)qr, q1=*(const float4*)(qr+4);
    const float* kr = hl + e*132 + hh*8;
    float4 k0=*(const float4*)kr, k1=*(const float4*)(kr+4);
    float s = q0.x*k0.x+q0.y*k0.y+q0.z*k0.z+q0.w*k0.w
            + q1.x*k1.x+q1.y*k1.y+q1.z*k1.z+q1.w*k1.w;
    s *= 0.35355339059327373f;
    scw[(size_t)(e0+e)*16 + hh] = s;
    atomicMax(&smx[d*16 + hh], fmap(s));
  }
}
__global__ void __launch_bounds__(256)
k_edge(const void* rfeat, const void* efeat, const int* ei,
       const void* ewW, const void* ewb,
       const void* kb1, const void* vb1,
       const void* klnw, const void* klnb, const void* vlnw, const void* vlnb,
       const void* kb2, const void* vb2,
       const unsigned short* w1sh, const unsigned short* w1sl,
       const unsigned short* w2kh, const unsigned short* w2kl,
       const unsigned short* w2vh, const unsigned short* w2vl,
       const float* hkd, const float* hks, const float* qws,
       float* scw, float* vsw, u32* smx, const int* flags){
  __shared__ float hdn[ET][260];
  __shared__ unsigned short ahi[ET*256];
  __shared__ unsigned short alo[ET*256];
  __shared__ unsigned short sfh[ET*32], sfl[ET*32];
  __shared__ int   dste[ET], srce[ET];
  __shared__ float ewv[ET];
  __shared__ float2 redp[256];
  __shared__ float mus[32], scs[32];
  bool i64 = flags[1] != 0;
  if (flags[0]) edge_body<true >(rfeat,efeat,ei,i64,ewW,ewb,kb1,vb1,klnw,klnb,vlnw,vlnb,kb2,vb2,
                                 w1sh,w1sl,w2kh,w2kl,w2vh,w2vl,hkd,hks,qws,scw,vsw,smx,
                                 hdn,ahi,alo,sfh,sfl,dste,srce,ewv,redp,mus,scs);
  else          edge_body<false>(rfeat,efeat,ei,i64,ewW,ewb,kb1,vb1,klnw,klnb,vlnw,vlnb,kb2,vb2,
                                 w1sh,w1sl,w2kh,w2kl,w2vh,w2vl,hkd,hks,qws,scw,vsw,smx,
                                 hdn,ahi,alo,sfh,sfl,dste,srce,ewv,redp,mus,scs);
}

// ================= denom =================
__global__ void __launch_bounds__(256)
k_den(const int* ei, const u32* smx, const float* scw, float* den, const int* flags){
  int t = blockIdx.x*256 + threadIdx.x;
  bool i64 = flags[1] != 0;
  int e = t>>4, hh = t&15;
  int d = gidx(ei, EE + e, i64);
  float m  = funmap(smx[d*16 + hh]);
  atomicAdd(&den[d*16 + hh], expf(scw[t] - m));
}

// ================= alpha*vs reduce + scatter =================
__global__ void __launch_bounds__(256)
k_out(const int* ei, const void* relx, const float* scw, const float* vsw,
      const u32* smx, const float* den, float* oac, const int* flags){
  int t = blockIdx.x*256 + threadIdx.x;
  bool bf  = flags[0] != 0;
  bool i64 = flags[1] != 0;
  int e = t>>4, hh = t&15;
  int d = gidx(ei, EE + e, i64);
  float m = funmap(smx[d*16 + hh]);
  float a = expf(scw[t] - m) / den[d*16 + hh] * vsw[t];
  a += __shfl_xor(a, 8, 16);
  a += __shfl_xor(a, 4, 16);
  a += __shfl_xor(a, 2, 16);
  a += __shfl_xor(a, 1, 16);
  if (hh < 3){
    float r = bf ? __bfloat162float(((const __hip_bfloat16*)relx)[e*3+hh])
                 : ((const float*)relx)[e*3+hh];
    atomicAdd(&oac[d*3 + hh], a * r);
  }
}

// ================= finalize =================
__global__ void __launch_bounds__(256)
k_fin(const float* oac, void* dout, const int* flags){
  int t = blockIdx.x*256 + threadIdx.x;
  if (t >= NN*3) return;
  if (flags[0]) ((__hip_bfloat16*)dout)[t] = __float2bfloat16(oac[t]);
  else          ((float*)dout)[t] = oac[t];
}

extern "C" void kernel_launch(void* const* d_in, const int* in_sizes, int n_in,
                              void* d_out, int out_size, void* d_ws, size_t ws_size,
                              hipStream_t stream){
  const void* h     = d_in[0];
  const void* relx  = d_in[1];
  const void* rfeat = d_in[2];
  const void* efeat = d_in[3];
  const int*  ei    = (const int*)d_in[4];
  const void* ewW   = d_in[5];
  const void* ewb   = d_in[6];
  const void* kW1 = d_in[7],  *kb1 = d_in[8],  *klnw = d_in[9],  *klnb = d_in[10], *kW2 = d_in[11], *kb2 = d_in[12];
  const void* vW1 = d_in[13], *vb1 = d_in[14], *vlnw = d_in[15], *vlnb = d_in[16], *vW2 = d_in[17], *vb2 = d_in[18];
  const void* qW1 = d_in[19], *qb1 = d_in[20], *qlnw = d_in[21], *qlnb = d_in[22], *qW2 = d_in[23], *qb2 = d_in[24];

  float* qws = (float*)d_ws;                         // N*128
  float* hkd = qws + (size_t)NN*128;                 // N*256
  float* hks = hkd + (size_t)NN*256;                 // N*256
  float* scw = hks + (size_t)NN*256;                 // E*16
  float* vsw = scw + (size_t)EE*16;                  // E*16
  u32*   smx = (u32*)(vsw + (size_t)EE*16);          // N*16
  float* den = (float*)(smx + (size_t)NN*16);        // N*16
  float* oac = den + (size_t)NN*16;                  // N*3
  unsigned short* w1sh = (unsigned short*)(oac + (size_t)NN*3);
  unsigned short* w1sl = w1sh + 8192;
  unsigned short* w2kh = w1sl + 8192;
  unsigned short* w2kl = w2kh + 16384;
  unsigned short* w2vh = w2kl + 16384;
  unsigned short* w2vl = w2vh + 2048;
  int* flags = (int*)(w2vl + 2048);

  hipMemsetAsync(smx, 0, ((size_t)NN*16*2 + (size_t)NN*3)*sizeof(float), stream);
  k_detect<<<1, 64, 0, stream>>>((const u32*)klnw, (const u32*)ei, flags);
  k_wprep<<<64, 256, 0, stream>>>(kW1, vW1, kW2, vW2, w1sh, w1sl, w2kh, w2kl, w2vh, w2vl, flags);
  k_node<<<NN/NT, 256, 0, stream>>>(h, kW1, vW1, hkd, hks, flags);
  k_q<<<NN/QT, 256, 0, stream>>>(h, qW1, qb1, qlnw, qlnb, qW2, qb2, qws, flags);
  k_edge<<<EE/ET, 256, 0, stream>>>(rfeat, efeat, ei, ewW, ewb,
                                    kb1, vb1, klnw, klnb, vlnw, vlnb, kb2, vb2,
                                    w1sh, w1sl, w2kh, w2kl, w2vh, w2vl,
                                    hkd, hks, qws, scw, vsw, smx, flags);
  k_den<<<(EE*16)/256, 256, 0, stream>>>(ei, smx, scw, den, flags);
  k_out<<<(EE*16)/256, 256, 0, stream>>>(ei, relx, scw, vsw, smx, den, oac, flags);
  k_fin<<<(NN*3 + 255)/256, 256, 0, stream>>>(oac, d_out, flags);
}